// Round 4
// baseline (244.175 us; speedup 1.0000x reference)
//
#include <hip/hip_runtime.h>

// B=8, L=1024, H=1024, NH=16, HD=64. fp32 I/O, bf16 MFMA internals.
// Pipeline: cvt3     : x,w_qkv,w_out fp32 -> bf16                  (~13 us)
//           gemm16<0>: qk = x@w_qkv^T cols<2048; V scatters to Vt  (51.5 GF)
//           attn     : no-max softmax flash attn, S^T trick        (34.4 GF)
//           gemm16<1>: out = O@w_out^T + b_out (fp32 out)          (17.2 GF)
// R14: gemm16 reverted to the proven R0 form (67us; R13 prefetch variant was
// 70.7 -> reverted). attn restructured for LDS-BW: it was LDS-read-bound
// (32 waves/CU x 256 ds_read_b128 x ~12cy ~= 41us of LDS occupancy/CU).
// kf depends only on (t,s,lane) and vf only on (jd,s,lane) -> one LDS read
// now feeds TWO q-fragment MFMAs: per wave 32 q-cols (qb=0,1), QBLK=128,
// grid (8,128)=1024 blocks, 3-4 blocks/CU. LDS reads per output halve
// (floor ~20.5us); K/V staging traffic halves too. MFMA/VALU totals equal.

typedef short s16x8 __attribute__((ext_vector_type(8)));
typedef float f32x4 __attribute__((ext_vector_type(4)));
typedef unsigned int u32x2 __attribute__((ext_vector_type(2)));
typedef unsigned int u32x4 __attribute__((ext_vector_type(4)));

__device__ __forceinline__ unsigned short f2bf(float f) {   // RNE
    union { float f; unsigned u; } c; c.f = f;
    return (unsigned short)((c.u + 0x7FFFu + ((c.u >> 16) & 1u)) >> 16);
}
// pack 2 floats -> 2 bf16 (round-half-up) in 3 VALU ops via v_perm
__device__ __forceinline__ unsigned pack2bf(float a, float b) {
    union { float f; unsigned u; } ca, cb; ca.f = a; cb.f = b;
    return __builtin_amdgcn_perm(cb.u + 0x8000u, ca.u + 0x8000u, 0x07060302u);
}

#define GLOAD_LDS(g, l) __builtin_amdgcn_global_load_lds( \
    (const __attribute__((address_space(1))) void*)(g),   \
    (__attribute__((address_space(3))) void*)(l), 16, 0, 0)

// ---------------------------------------------------------------------------
// fp32 -> bf16 convert for the three input tensors.
// ---------------------------------------------------------------------------
__global__ __launch_bounds__(256) void cvt3(
    const float* __restrict__ s0, unsigned short* __restrict__ d0, int n0,
    const float* __restrict__ s1, unsigned short* __restrict__ d1, int n1,
    const float* __restrict__ s2, unsigned short* __restrict__ d2, int n2)
{
    long i = ((long)blockIdx.x * 256 + threadIdx.x) * 8;
    const float* s; unsigned short* d; long off;
    if (i < n0)                  { s = s0; d = d0; off = i; }
    else if (i < (long)n0 + n1)  { s = s1; d = d1; off = i - n0; }
    else                         { s = s2; d = d2; off = i - n0 - n1; }
    f32x4 a = *(const f32x4*)(s + off);
    f32x4 b = *(const f32x4*)(s + off + 4);
    u32x4 r;
    r[0] = pack2bf(a[0], a[1]); r[1] = pack2bf(a[2], a[3]);
    r[2] = pack2bf(b[0], b[1]); r[3] = pack2bf(b[2], b[3]);
    *(u32x4*)(d + off) = r;
}

// ---------------------------------------------------------------------------
// GEMM: C[M,N] = A[M,K]*B[N,K]^T, bf16 in, fp32 accum. 128x128 tile, BK=64,
// global_load_lds dwordx4. LDS [128][64] elems, XOR swizzle: logical 16B
// chunk q of row r at physical chunk q ^ (r&7) -> 2-way on banks (free).
// EPI=0: cols<1024 (Q) -> Cq bf16 scaled by 0.125*log2(e) (softmax prefold);
//        cols 1024..2047 (K) -> Cq bf16 unscaled; cols>=2048 (V) packed-
//        scatter to Cv = Vt[(b*16+h)*64+d][l] bf16.
// EPI=1: Cf fp32 + bias.
// ---------------------------------------------------------------------------
template<int EPI>
__global__ __launch_bounds__(256) void gemm16(
    const unsigned short* __restrict__ A, const unsigned short* __restrict__ Bm,
    unsigned short* __restrict__ Cq, unsigned short* __restrict__ Cv,
    float* __restrict__ Cf, const float* __restrict__ bias,
    int N, int K)
{
    __shared__ unsigned short As[128 * 64];
    __shared__ unsigned short Bs[128 * 64];
    const int tid = threadIdx.x, lane = tid & 63, wave = tid >> 6;
    const int quad = lane >> 4, l16 = lane & 15;
    const int wm = (wave >> 1) * 64, wn = (wave & 1) * 64;
    const int m0 = blockIdx.y * 128, n0 = blockIdx.x * 128;

    const int prow = tid >> 3;
    const int qch  = (tid & 7) ^ (prow & 7);
    const unsigned short* gA[4];
    const unsigned short* gB[4];
    #pragma unroll
    for (int c = 0; c < 4; ++c) {
        gA[c] = A + (size_t)(m0 + c * 32 + prow) * K + qch * 8;
        gB[c] = Bm + (size_t)(n0 + c * 32 + prow) * K + qch * 8;
    }
    const int sw = l16 & 7;   // frag-read swizzle

    f32x4 acc[4][4] = {};
    for (int k0 = 0; k0 < K; k0 += 64) {
        __syncthreads();
        #pragma unroll
        for (int c = 0; c < 4; ++c) {
            GLOAD_LDS(gA[c], As + (c * 256 + tid) * 8);
            GLOAD_LDS(gB[c], Bs + (c * 256 + tid) * 8);
            gA[c] += 64; gB[c] += 64;
        }
        __syncthreads();
        #pragma unroll
        for (int s = 0; s < 2; ++s) {
            s16x8 af[4], bf[4];
            const int pc = ((s * 4 + quad) ^ sw) * 8;
            #pragma unroll
            for (int i = 0; i < 4; ++i)
                af[i] = *(const s16x8*)(As + (wm + i * 16 + l16) * 64 + pc);
            #pragma unroll
            for (int j = 0; j < 4; ++j)
                bf[j] = *(const s16x8*)(Bs + (wn + j * 16 + l16) * 64 + pc);
            #pragma unroll
            for (int i = 0; i < 4; ++i)
                #pragma unroll
                for (int j = 0; j < 4; ++j)
                    acc[i][j] = __builtin_amdgcn_mfma_f32_16x16x32_bf16(af[i], bf[j], acc[i][j], 0, 0, 0);
        }
    }

    // epilogue: C/D layout col=lane&15, row=quad*4+reg
    if (EPI == 1) {
        #pragma unroll
        for (int j = 0; j < 4; ++j) {
            int col = n0 + wn + j * 16 + l16;
            float bv = bias[col];
            #pragma unroll
            for (int i = 0; i < 4; ++i)
                #pragma unroll
                for (int r = 0; r < 4; ++r)
                    Cf[(size_t)(m0 + wm + i * 16 + quad * 4 + r) * N + col] = acc[i][j][r] + bv;
        }
    } else if (n0 < 2048) {
        // Q region: prefold softmax scale (1/8) and log2(e) for native exp2
        const float qs = (n0 < 1024) ? 0.18033688f : 1.0f;   // 0.125*log2(e)
        #pragma unroll
        for (int j = 0; j < 4; ++j) {
            int col = n0 + wn + j * 16 + l16;
            #pragma unroll
            for (int i = 0; i < 4; ++i)
                #pragma unroll
                for (int r = 0; r < 4; ++r)
                    Cq[(size_t)(m0 + wm + i * 16 + quad * 4 + r) * 2048 + col] = f2bf(acc[i][j][r] * qs);
        }
    } else {
        // V region: lane's r=0..3 are 4 consecutive l -> one 8B packed store
        #pragma unroll
        for (int j = 0; j < 4; ++j) {
            int dcol = n0 + wn + j * 16 + l16 - 2048;
            int hh = dcol >> 6, dd = dcol & 63;
            #pragma unroll
            for (int i = 0; i < 4; ++i) {
                int row = m0 + wm + i * 16 + quad * 4;
                int bb = row >> 10, l = row & 1023;
                u32x2 pw;
                pw[0] = pack2bf(acc[i][j][0], acc[i][j][1]);
                pw[1] = pack2bf(acc[i][j][2], acc[i][j][3]);
                *(u32x2*)(Cv + (size_t)((bb * 16 + hh) * 64 + dd) * 1024 + l) = pw;
            }
        }
    }
}

// ---------------------------------------------------------------------------
// Flash attention, no-max softmax (Q pre-scaled by 0.125*log2e -> bare exp2),
// S^T trick with kv-permuted K staging so P's packed C-layout registers are
// directly the PV A-fragments (no P LDS round-trip).
// K staging permutation: LDS row rho = 16t+4u+r holds kv = 32(t>>1)+8u+4(t&1)+r.
// R14: 32 q-cols per wave (qb=0,1) sharing each kf/vf LDS read -> LDS-read
// traffic per output halves (attn was LDS-BW-bound). 128 q-rows/block,
// grid (8 qtile, 128 bh) = 1024 blocks, ~3 blocks/CU. LDS 16.4 KB.
// MFMA clusters setprio(1)-wrapped (independent blocks at different phases).
// ---------------------------------------------------------------------------
__global__ __launch_bounds__(256) void attn(
    const unsigned short* __restrict__ qk, const unsigned short* __restrict__ Vt,
    unsigned short* __restrict__ O)
{
    __shared__ unsigned short Ks[64 * 64];   // [rho][d] kv-permuted, swizzled
    __shared__ unsigned short Vs[64 * 64];   // [d][kv]  natural, swizzled

    const int bh = blockIdx.y, b = bh >> 4, hh = bh & 15;
    const int q0 = blockIdx.x * 128;
    const int tid = threadIdx.x, lane = tid & 63, wave = tid >> 6;
    const int quad = lane >> 4, l16 = lane & 15;

    // Q frags direct from global: B-operand, n=q=wave*32+qb*16+l16,
    // k=s*32+quad*8
    s16x8 qf[2][2];
    #pragma unroll
    for (int qb = 0; qb < 2; ++qb) {
        const unsigned short* qrow =
            qk + (size_t)(b * 1024 + q0 + wave * 32 + qb * 16 + l16) * 2048 + hh * 64;
        qf[qb][0] = *(const s16x8*)(qrow + quad * 8);
        qf[qb][1] = *(const s16x8*)(qrow + 32 + quad * 8);
    }

    // Staging: wave covers LDS rows rho0 = wave*16+rl and rho1 = rho0+8
    // (rl = lane>>3); chunk swizzle qc = (lane&7) ^ (rho&7), rho&7 == rl.
    // K source rows are the PERMUTED kv for each rho (t = wave for both).
    const int rl = lane >> 3;
    const int qc = (lane & 7) ^ rl;
    const int u0 = rl >> 2, r0 = rl & 3;
    const int kvbase = 32 * (wave >> 1) + 4 * (wave & 1) + r0;
    const int kv0 = kvbase + 8 * u0;          // for LDS row wave*16 + rl
    const int kv1 = kvbase + 8 * (2 + u0);    // for LDS row wave*16 + 8 + rl
    const unsigned short* srcK0 = qk + (size_t)(b * 1024 + kv0) * 2048 + 1024 + hh * 64 + qc * 8;
    const unsigned short* srcK1 = qk + (size_t)(b * 1024 + kv1) * 2048 + 1024 + hh * 64 + qc * 8;
    const unsigned short* srcV0 = Vt + (size_t)(bh * 64 + wave * 16 + rl) * 1024 + qc * 8;
    const unsigned short* srcV1 = Vt + (size_t)(bh * 64 + wave * 16 + 8 + rl) * 1024 + qc * 8;
    unsigned short* dK0 = Ks + (wave * 16 + rl) * 64 + (lane & 7) * 8;
    unsigned short* dK1 = Ks + (wave * 16 + 8 + rl) * 64 + (lane & 7) * 8;
    unsigned short* dV0 = Vs + (wave * 16 + rl) * 64 + (lane & 7) * 8;
    unsigned short* dV1 = Vs + (wave * 16 + 8 + rl) * 64 + (lane & 7) * 8;

    const int sw = l16 & 7;   // frag-read swizzle

    f32x4 Oacc[4][2] = {};
    float lsum[2] = {0.0f, 0.0f};

    for (int kv = 0; kv < 1024; kv += 64) {
        __syncthreads();
        GLOAD_LDS(srcK0, dK0);
        GLOAD_LDS(srcK1, dK1);
        GLOAD_LDS(srcV0, dV0);
        GLOAD_LDS(srcV1, dV1);
        srcK0 += (size_t)64 * 2048; srcK1 += (size_t)64 * 2048;
        srcV0 += 64; srcV1 += 64;
        __syncthreads();   // vmcnt(0) drain -> K,V in LDS

        // S^T = K Q^T : tile t rows = permuted kv, col q; one kf read feeds
        // both q-fragments (kf independent of qb)
        f32x4 Sacc[4][2] = {};
        __builtin_amdgcn_s_setprio(1);
        #pragma unroll
        for (int t = 0; t < 4; ++t) {
            #pragma unroll
            for (int s = 0; s < 2; ++s) {
                s16x8 kf = *(const s16x8*)(Ks + (t * 16 + l16) * 64 + ((s * 4 + quad) ^ sw) * 8);
                #pragma unroll
                for (int qb = 0; qb < 2; ++qb)
                    Sacc[t][qb] = __builtin_amdgcn_mfma_f32_16x16x32_bf16(kf, qf[qb][s], Sacc[t][qb], 0, 0, 0);
            }
        }
        __builtin_amdgcn_s_setprio(0);
        // p = 2^s; per-lane row-sum; pack pairs (these ARE the PV A-frags)
        unsigned upw[4][2][2];
        #pragma unroll
        for (int t = 0; t < 4; ++t) {
            #pragma unroll
            for (int qb = 0; qb < 2; ++qb) {
                float p0 = __builtin_amdgcn_exp2f(Sacc[t][qb][0]);
                float p1 = __builtin_amdgcn_exp2f(Sacc[t][qb][1]);
                float p2 = __builtin_amdgcn_exp2f(Sacc[t][qb][2]);
                float p3 = __builtin_amdgcn_exp2f(Sacc[t][qb][3]);
                lsum[qb] += (p0 + p1) + (p2 + p3);
                upw[t][qb][0] = pack2bf(p0, p1);
                upw[t][qb][1] = pack2bf(p2, p3);
            }
        }
        // O += P V^T : A = packed P (register), B = Vs[n=d] (natural);
        // one vf read feeds both q-fragments (vf independent of qb)
        __builtin_amdgcn_s_setprio(1);
        #pragma unroll
        for (int s = 0; s < 2; ++s) {
            s16x8 pf[2];
            #pragma unroll
            for (int qb = 0; qb < 2; ++qb) {
                u32x4 aw;
                aw[0] = upw[2 * s][qb][0];     aw[1] = upw[2 * s][qb][1];
                aw[2] = upw[2 * s + 1][qb][0]; aw[3] = upw[2 * s + 1][qb][1];
                __builtin_memcpy(&pf[qb], &aw, 16);
            }
            #pragma unroll
            for (int jd = 0; jd < 4; ++jd) {
                s16x8 vf = *(const s16x8*)(Vs + (jd * 16 + l16) * 64 + ((s * 4 + quad) ^ sw) * 8);
                #pragma unroll
                for (int qb = 0; qb < 2; ++qb)
                    Oacc[jd][qb] = __builtin_amdgcn_mfma_f32_16x16x32_bf16(pf[qb], vf, Oacc[jd][qb], 0, 0, 0);
            }
        }
        __builtin_amdgcn_s_setprio(0);
    }

    // row-sum reduce + write (sum over quads is permutation-invariant)
    #pragma unroll
    for (int qb = 0; qb < 2; ++qb) {
        float ls = lsum[qb];
        ls += __shfl_xor(ls, 16, 64);
        ls += __shfl_xor(ls, 32, 64);
        float rinv[4];
        #pragma unroll
        for (int r = 0; r < 4; ++r)
            rinv[r] = 1.0f / __shfl(ls, quad * 4 + r, 64);
        #pragma unroll
        for (int j = 0; j < 4; ++j)
            #pragma unroll
            for (int r = 0; r < 4; ++r) {
                int row = q0 + wave * 32 + qb * 16 + quad * 4 + r;
                int col = hh * 64 + j * 16 + l16;
                O[(size_t)(b * 1024 + row) * 1024 + col] = f2bf(Oacc[j][qb][r] * rinv[r]);
            }
    }
}

extern "C" void kernel_launch(void* const* d_in, const int* in_sizes, int n_in,
                              void* d_out, int out_size, void* d_ws, size_t ws_size,
                              hipStream_t stream) {
    const float* x     = (const float*)d_in[0];   // [8192,1024]
    const float* w_qkv = (const float*)d_in[1];   // [3072,1024]
    const float* w_out = (const float*)d_in[2];   // [1024,1024]
    const float* b_out = (const float*)d_in[3];   // [1024]
    float* out = (float*)d_out;                   // [8192,1024] fp32

    const int nx = 8192 * 1024, nwq = 3072 * 1024, nwo = 1024 * 1024;
    unsigned short* xb  = (unsigned short*)d_ws;          // 16.8 MB (dead after gemm1)
    unsigned short* wqb = xb + nx;                        //  6.3 MB
    unsigned short* wob = wqb + nwq;                      //  2.1 MB
    unsigned short* qkb = wob + nwo;                      // [8192,2048] Q|K, 33.6 MB
    unsigned short* Vt  = qkb + (size_t)8192 * 2048;      // [128*64,1024], 16.8 MB
    unsigned short* Ob  = xb;                             // alias: xb dead after gemm1

    dim3 blk(256);
    cvt3<<<6144, blk, 0, stream>>>(x, xb, nx, w_qkv, wqb, nwq, w_out, wob, nwo);
    gemm16<0><<<dim3(24, 64), blk, 0, stream>>>(xb, wqb, qkb, Vt, nullptr, nullptr, 3072, 1024);
    attn<<<dim3(8, 128), blk, 0, stream>>>(qkb, Vt, Ob);
    gemm16<1><<<dim3(8, 64), blk, 0, stream>>>(Ob, wob, nullptr, nullptr, out, b_out, 1024, 1024);
}

// Round 5
// 241.014 us; speedup vs baseline: 1.0131x; 1.0131x over previous
//
#include <hip/hip_runtime.h>

// B=8, L=1024, H=1024, NH=16, HD=64. fp32 I/O, bf16 MFMA internals.
// Pipeline: cvt3     : x,w_qkv,w_out fp32 -> bf16                  (~13 us)
//           gemm16<0>: qk = x@w_qkv^T cols<2048; V scatters to Vt  (51.5 GF)
//           attn     : no-max softmax flash attn, S^T trick        (34.4 GF)
//           gemm16<1>: out = O@w_out^T + b_out (fp32 out)          (17.2 GF)
// R15: attn = R14's q-widening (one kf/vf LDS read feeds 2 q-frags -> LDS
// traffic per output halved) BUT with 2-wave 128-thread blocks, QBLK=64,
// grid (16,128)=2048 blocks = 8 blocks/CU restored. R14 proved attn is
// latency-bound (TLP-starved at 4 blocks/CU: 55 -> 66.4 us); this keeps
// R0's 8 phase-independent blocks per CU AND half the LDS/staging work.
// Each wave stages 8 GLOADs: K row-tiles t=2w,2w+1 (kv offsets {0,16,4,20}
// from kvbase = 32w+8u0+r0) + V rows 32w+8j+rl. All dest rows == rl mod 8
// so the chunk pre-swizzle qc=(lane&7)^rl is unchanged.
// gemm16 = proven R0 form (67us, 769TF; R11/R12/R13 schedule variants all
// regressed and are reverted).

typedef short s16x8 __attribute__((ext_vector_type(8)));
typedef float f32x4 __attribute__((ext_vector_type(4)));
typedef unsigned int u32x2 __attribute__((ext_vector_type(2)));
typedef unsigned int u32x4 __attribute__((ext_vector_type(4)));

__device__ __forceinline__ unsigned short f2bf(float f) {   // RNE
    union { float f; unsigned u; } c; c.f = f;
    return (unsigned short)((c.u + 0x7FFFu + ((c.u >> 16) & 1u)) >> 16);
}
// pack 2 floats -> 2 bf16 (round-half-up) in 3 VALU ops via v_perm
__device__ __forceinline__ unsigned pack2bf(float a, float b) {
    union { float f; unsigned u; } ca, cb; ca.f = a; cb.f = b;
    return __builtin_amdgcn_perm(cb.u + 0x8000u, ca.u + 0x8000u, 0x07060302u);
}

#define GLOAD_LDS(g, l) __builtin_amdgcn_global_load_lds( \
    (const __attribute__((address_space(1))) void*)(g),   \
    (__attribute__((address_space(3))) void*)(l), 16, 0, 0)

// ---------------------------------------------------------------------------
// fp32 -> bf16 convert for the three input tensors.
// ---------------------------------------------------------------------------
__global__ __launch_bounds__(256) void cvt3(
    const float* __restrict__ s0, unsigned short* __restrict__ d0, int n0,
    const float* __restrict__ s1, unsigned short* __restrict__ d1, int n1,
    const float* __restrict__ s2, unsigned short* __restrict__ d2, int n2)
{
    long i = ((long)blockIdx.x * 256 + threadIdx.x) * 8;
    const float* s; unsigned short* d; long off;
    if (i < n0)                  { s = s0; d = d0; off = i; }
    else if (i < (long)n0 + n1)  { s = s1; d = d1; off = i - n0; }
    else                         { s = s2; d = d2; off = i - n0 - n1; }
    f32x4 a = *(const f32x4*)(s + off);
    f32x4 b = *(const f32x4*)(s + off + 4);
    u32x4 r;
    r[0] = pack2bf(a[0], a[1]); r[1] = pack2bf(a[2], a[3]);
    r[2] = pack2bf(b[0], b[1]); r[3] = pack2bf(b[2], b[3]);
    *(u32x4*)(d + off) = r;
}

// ---------------------------------------------------------------------------
// GEMM: C[M,N] = A[M,K]*B[N,K]^T, bf16 in, fp32 accum. 128x128 tile, BK=64,
// global_load_lds dwordx4. LDS [128][64] elems, XOR swizzle: logical 16B
// chunk q of row r at physical chunk q ^ (r&7) -> 2-way on banks (free).
// EPI=0: cols<1024 (Q) -> Cq bf16 scaled by 0.125*log2(e) (softmax prefold);
//        cols 1024..2047 (K) -> Cq bf16 unscaled; cols>=2048 (V) packed-
//        scatter to Cv = Vt[(b*16+h)*64+d][l] bf16.
// EPI=1: Cf fp32 + bias.
// ---------------------------------------------------------------------------
template<int EPI>
__global__ __launch_bounds__(256) void gemm16(
    const unsigned short* __restrict__ A, const unsigned short* __restrict__ Bm,
    unsigned short* __restrict__ Cq, unsigned short* __restrict__ Cv,
    float* __restrict__ Cf, const float* __restrict__ bias,
    int N, int K)
{
    __shared__ unsigned short As[128 * 64];
    __shared__ unsigned short Bs[128 * 64];
    const int tid = threadIdx.x, lane = tid & 63, wave = tid >> 6;
    const int quad = lane >> 4, l16 = lane & 15;
    const int wm = (wave >> 1) * 64, wn = (wave & 1) * 64;
    const int m0 = blockIdx.y * 128, n0 = blockIdx.x * 128;

    const int prow = tid >> 3;
    const int qch  = (tid & 7) ^ (prow & 7);
    const unsigned short* gA[4];
    const unsigned short* gB[4];
    #pragma unroll
    for (int c = 0; c < 4; ++c) {
        gA[c] = A + (size_t)(m0 + c * 32 + prow) * K + qch * 8;
        gB[c] = Bm + (size_t)(n0 + c * 32 + prow) * K + qch * 8;
    }
    const int sw = l16 & 7;   // frag-read swizzle

    f32x4 acc[4][4] = {};
    for (int k0 = 0; k0 < K; k0 += 64) {
        __syncthreads();
        #pragma unroll
        for (int c = 0; c < 4; ++c) {
            GLOAD_LDS(gA[c], As + (c * 256 + tid) * 8);
            GLOAD_LDS(gB[c], Bs + (c * 256 + tid) * 8);
            gA[c] += 64; gB[c] += 64;
        }
        __syncthreads();
        #pragma unroll
        for (int s = 0; s < 2; ++s) {
            s16x8 af[4], bf[4];
            const int pc = ((s * 4 + quad) ^ sw) * 8;
            #pragma unroll
            for (int i = 0; i < 4; ++i)
                af[i] = *(const s16x8*)(As + (wm + i * 16 + l16) * 64 + pc);
            #pragma unroll
            for (int j = 0; j < 4; ++j)
                bf[j] = *(const s16x8*)(Bs + (wn + j * 16 + l16) * 64 + pc);
            #pragma unroll
            for (int i = 0; i < 4; ++i)
                #pragma unroll
                for (int j = 0; j < 4; ++j)
                    acc[i][j] = __builtin_amdgcn_mfma_f32_16x16x32_bf16(af[i], bf[j], acc[i][j], 0, 0, 0);
        }
    }

    // epilogue: C/D layout col=lane&15, row=quad*4+reg
    if (EPI == 1) {
        #pragma unroll
        for (int j = 0; j < 4; ++j) {
            int col = n0 + wn + j * 16 + l16;
            float bv = bias[col];
            #pragma unroll
            for (int i = 0; i < 4; ++i)
                #pragma unroll
                for (int r = 0; r < 4; ++r)
                    Cf[(size_t)(m0 + wm + i * 16 + quad * 4 + r) * N + col] = acc[i][j][r] + bv;
        }
    } else if (n0 < 2048) {
        // Q region: prefold softmax scale (1/8) and log2(e) for native exp2
        const float qs = (n0 < 1024) ? 0.18033688f : 1.0f;   // 0.125*log2(e)
        #pragma unroll
        for (int j = 0; j < 4; ++j) {
            int col = n0 + wn + j * 16 + l16;
            #pragma unroll
            for (int i = 0; i < 4; ++i)
                #pragma unroll
                for (int r = 0; r < 4; ++r)
                    Cq[(size_t)(m0 + wm + i * 16 + quad * 4 + r) * 2048 + col] = f2bf(acc[i][j][r] * qs);
        }
    } else {
        // V region: lane's r=0..3 are 4 consecutive l -> one 8B packed store
        #pragma unroll
        for (int j = 0; j < 4; ++j) {
            int dcol = n0 + wn + j * 16 + l16 - 2048;
            int hh = dcol >> 6, dd = dcol & 63;
            #pragma unroll
            for (int i = 0; i < 4; ++i) {
                int row = m0 + wm + i * 16 + quad * 4;
                int bb = row >> 10, l = row & 1023;
                u32x2 pw;
                pw[0] = pack2bf(acc[i][j][0], acc[i][j][1]);
                pw[1] = pack2bf(acc[i][j][2], acc[i][j][3]);
                *(u32x2*)(Cv + (size_t)((bb * 16 + hh) * 64 + dd) * 1024 + l) = pw;
            }
        }
    }
}

// ---------------------------------------------------------------------------
// Flash attention, no-max softmax (Q pre-scaled by 0.125*log2e -> bare exp2),
// S^T trick with kv-permuted K staging so P's packed C-layout registers are
// directly the PV A-fragments (no P LDS round-trip).
// K staging permutation: LDS row rho = 16t+4u+r holds kv = 32(t>>1)+8u+4(t&1)+r.
// R15: 2 waves/block (128 thr), 32 q-cols per wave (qb=0,1) sharing each
// kf/vf LDS read. QBLK=64, grid (16,128) = 2048 blocks = 8 blocks/CU of
// independent phase -> latency hiding of R0 with HALF the LDS/staging
// traffic. Wave w stages K row-tiles t=2w,2w+1 + V rows 32w..32w+31
// (8 GLOADs/wave). LDS 16.4 KB. MFMA clusters setprio(1)-wrapped.
// ---------------------------------------------------------------------------
__global__ __launch_bounds__(128) void attn(
    const unsigned short* __restrict__ qk, const unsigned short* __restrict__ Vt,
    unsigned short* __restrict__ O)
{
    __shared__ unsigned short Ks[64 * 64];   // [rho][d] kv-permuted, swizzled
    __shared__ unsigned short Vs[64 * 64];   // [d][kv]  natural, swizzled

    const int bh = blockIdx.y, b = bh >> 4, hh = bh & 15;
    const int q0 = blockIdx.x * 64;
    const int tid = threadIdx.x, lane = tid & 63, wave = tid >> 6;  // wave 0..1
    const int quad = lane >> 4, l16 = lane & 15;

    // Q frags direct from global: B-operand, n=q=wave*32+qb*16+l16,
    // k=s*32+quad*8
    s16x8 qf[2][2];
    #pragma unroll
    for (int qb = 0; qb < 2; ++qb) {
        const unsigned short* qrow =
            qk + (size_t)(b * 1024 + q0 + wave * 32 + qb * 16 + l16) * 2048 + hh * 64;
        qf[qb][0] = *(const s16x8*)(qrow + quad * 8);
        qf[qb][1] = *(const s16x8*)(qrow + 32 + quad * 8);
    }

    // Staging: wave w covers LDS rows 32w + 8j + rl (j=0..3, rl=lane>>3) for
    // both Ks and Vs; chunk swizzle qc = (lane&7) ^ (rho&7), rho&7 == rl.
    // K: rows 32w+rl / +8 / +16 / +24 are row-tiles t=2w (u=u0,2+u0) and
    // t=2w+1 (u=u0,2+u0); kv(t,u,r) = 32(t>>1)+8u+4(t&1)+r ->
    // kv = kvb + {0,16,4,20}[j] with kvb = 32w + 8*u0 + r0.
    const int rl = lane >> 3;
    const int qc = (lane & 7) ^ rl;
    const int u0 = rl >> 2, r0 = rl & 3;
    const int kvb = 32 * wave + 8 * u0 + r0;
    const unsigned short* srcK[4];
    const unsigned short* srcV[4];
    unsigned short* dK[4];
    unsigned short* dV[4];
    const int kvoff[4] = {0, 16, 4, 20};
    #pragma unroll
    for (int j = 0; j < 4; ++j) {
        srcK[j] = qk + (size_t)(b * 1024 + kvb + kvoff[j]) * 2048 + 1024 + hh * 64 + qc * 8;
        srcV[j] = Vt + (size_t)(bh * 64 + 32 * wave + j * 8 + rl) * 1024 + qc * 8;
        dK[j] = Ks + (32 * wave + j * 8 + rl) * 64 + (lane & 7) * 8;
        dV[j] = Vs + (32 * wave + j * 8 + rl) * 64 + (lane & 7) * 8;
    }

    const int sw = l16 & 7;   // frag-read swizzle

    f32x4 Oacc[4][2] = {};
    float lsum[2] = {0.0f, 0.0f};

    for (int kv = 0; kv < 1024; kv += 64) {
        __syncthreads();
        #pragma unroll
        for (int j = 0; j < 4; ++j) {
            GLOAD_LDS(srcK[j], dK[j]);
            GLOAD_LDS(srcV[j], dV[j]);
            srcK[j] += (size_t)64 * 2048;
            srcV[j] += 64;
        }
        __syncthreads();   // vmcnt(0) drain -> K,V in LDS

        // S^T = K Q^T : tile t rows = permuted kv, col q; one kf read feeds
        // both q-fragments (kf independent of qb)
        f32x4 Sacc[4][2] = {};
        __builtin_amdgcn_s_setprio(1);
        #pragma unroll
        for (int t = 0; t < 4; ++t) {
            #pragma unroll
            for (int s = 0; s < 2; ++s) {
                s16x8 kf = *(const s16x8*)(Ks + (t * 16 + l16) * 64 + ((s * 4 + quad) ^ sw) * 8);
                #pragma unroll
                for (int qb = 0; qb < 2; ++qb)
                    Sacc[t][qb] = __builtin_amdgcn_mfma_f32_16x16x32_bf16(kf, qf[qb][s], Sacc[t][qb], 0, 0, 0);
            }
        }
        __builtin_amdgcn_s_setprio(0);
        // p = 2^s; per-lane row-sum; pack pairs (these ARE the PV A-frags)
        unsigned upw[4][2][2];
        #pragma unroll
        for (int t = 0; t < 4; ++t) {
            #pragma unroll
            for (int qb = 0; qb < 2; ++qb) {
                float p0 = __builtin_amdgcn_exp2f(Sacc[t][qb][0]);
                float p1 = __builtin_amdgcn_exp2f(Sacc[t][qb][1]);
                float p2 = __builtin_amdgcn_exp2f(Sacc[t][qb][2]);
                float p3 = __builtin_amdgcn_exp2f(Sacc[t][qb][3]);
                lsum[qb] += (p0 + p1) + (p2 + p3);
                upw[t][qb][0] = pack2bf(p0, p1);
                upw[t][qb][1] = pack2bf(p2, p3);
            }
        }
        // O += P V^T : A = packed P (register), B = Vs[n=d] (natural);
        // one vf read feeds both q-fragments (vf independent of qb)
        __builtin_amdgcn_s_setprio(1);
        #pragma unroll
        for (int s = 0; s < 2; ++s) {
            s16x8 pf[2];
            #pragma unroll
            for (int qb = 0; qb < 2; ++qb) {
                u32x4 aw;
                aw[0] = upw[2 * s][qb][0];     aw[1] = upw[2 * s][qb][1];
                aw[2] = upw[2 * s + 1][qb][0]; aw[3] = upw[2 * s + 1][qb][1];
                __builtin_memcpy(&pf[qb], &aw, 16);
            }
            #pragma unroll
            for (int jd = 0; jd < 4; ++jd) {
                s16x8 vf = *(const s16x8*)(Vs + (jd * 16 + l16) * 64 + ((s * 4 + quad) ^ sw) * 8);
                #pragma unroll
                for (int qb = 0; qb < 2; ++qb)
                    Oacc[jd][qb] = __builtin_amdgcn_mfma_f32_16x16x32_bf16(pf[qb], vf, Oacc[jd][qb], 0, 0, 0);
            }
        }
        __builtin_amdgcn_s_setprio(0);
    }

    // row-sum reduce + write (sum over quads is permutation-invariant)
    #pragma unroll
    for (int qb = 0; qb < 2; ++qb) {
        float ls = lsum[qb];
        ls += __shfl_xor(ls, 16, 64);
        ls += __shfl_xor(ls, 32, 64);
        float rinv[4];
        #pragma unroll
        for (int r = 0; r < 4; ++r)
            rinv[r] = 1.0f / __shfl(ls, quad * 4 + r, 64);
        #pragma unroll
        for (int j = 0; j < 4; ++j)
            #pragma unroll
            for (int r = 0; r < 4; ++r) {
                int row = q0 + wave * 32 + qb * 16 + quad * 4 + r;
                int col = hh * 64 + j * 16 + l16;
                O[(size_t)(b * 1024 + row) * 1024 + col] = f2bf(Oacc[j][qb][r] * rinv[r]);
            }
    }
}

extern "C" void kernel_launch(void* const* d_in, const int* in_sizes, int n_in,
                              void* d_out, int out_size, void* d_ws, size_t ws_size,
                              hipStream_t stream) {
    const float* x     = (const float*)d_in[0];   // [8192,1024]
    const float* w_qkv = (const float*)d_in[1];   // [3072,1024]
    const float* w_out = (const float*)d_in[2];   // [1024,1024]
    const float* b_out = (const float*)d_in[3];   // [1024]
    float* out = (float*)d_out;                   // [8192,1024] fp32

    const int nx = 8192 * 1024, nwq = 3072 * 1024, nwo = 1024 * 1024;
    unsigned short* xb  = (unsigned short*)d_ws;          // 16.8 MB (dead after gemm1)
    unsigned short* wqb = xb + nx;                        //  6.3 MB
    unsigned short* wob = wqb + nwq;                      //  2.1 MB
    unsigned short* qkb = wob + nwo;                      // [8192,2048] Q|K, 33.6 MB
    unsigned short* Vt  = qkb + (size_t)8192 * 2048;      // [128*64,1024], 16.8 MB
    unsigned short* Ob  = xb;                             // alias: xb dead after gemm1

    dim3 blk(256);
    cvt3<<<6144, blk, 0, stream>>>(x, xb, nx, w_qkv, wqb, nwq, w_out, wob, nwo);
    gemm16<0><<<dim3(24, 64), blk, 0, stream>>>(xb, wqb, qkb, Vt, nullptr, nullptr, 3072, 1024);
    attn<<<dim3(16, 128), dim3(128), 0, stream>>>(qkb, Vt, Ob);
    gemm16<1><<<dim3(8, 64), blk, 0, stream>>>(Ob, wob, nullptr, nullptr, out, b_out, 1024, 1024);
}

// Round 6
// 238.480 us; speedup vs baseline: 1.0239x; 1.0106x over previous
//
#include <hip/hip_runtime.h>

// B=8, L=1024, H=1024, NH=16, HD=64. fp32 I/O, bf16 MFMA internals.
// Pipeline: cvt3     : x,w_qkv,w_out fp32 -> bf16                  (~13 us)
//           gemm16<0>: qk = x@w_qkv^T cols<2048; V scatters to Vt  (51.5 GF)
//           attn     : no-max softmax flash attn, S^T trick        (34.4 GF)
//           gemm16<1>: out = O@w_out^T + b_out (fp32 out)          (17.2 GF)
// R16 (attn): R14 4-wave/qb-widened base (best measured, 66.4us) + two
// counter-matched fixes:
//  (a) XCD swizzle: R5 counters showed FETCH 142MB vs ~50MB ideal (3x L2
//      over-fill: the q-tile blocks sharing one bh's K/V scatter across all
//      8 XCDs). swz=(lin&7)*128+(lin>>3), qt=swz&7, bh=swz>>3 -> each bh's
//      8 blocks on ONE XCD; per-XCD set = 16bh x 256KB = 4MB ~ L2.
//  (b) 1-sync prefetch double-buffer (T3-minimum): LDS 16.4->32.8 KB,
//      loop = {__syncthreads(); stage(t+1 -> other buf); compute(t)}.
//      The stage issued in iter t drains at the TOP of t+1 -> full compute
//      phase (~800cy) covers the L2 fill latency that the old
//      sync;load;sync(vmcnt0);compute loop exposed every tile. 4 blocks/CU
//      unchanged (4 x 32.8KB <= 160KB).
// gemm16 = proven R0 form (67us/769TF; R11/R12/R13 schedule variants all
// regressed -> reverted, do not touch).

typedef short s16x8 __attribute__((ext_vector_type(8)));
typedef float f32x4 __attribute__((ext_vector_type(4)));
typedef unsigned int u32x2 __attribute__((ext_vector_type(2)));
typedef unsigned int u32x4 __attribute__((ext_vector_type(4)));

__device__ __forceinline__ unsigned short f2bf(float f) {   // RNE
    union { float f; unsigned u; } c; c.f = f;
    return (unsigned short)((c.u + 0x7FFFu + ((c.u >> 16) & 1u)) >> 16);
}
// pack 2 floats -> 2 bf16 (round-half-up) in 3 VALU ops via v_perm
__device__ __forceinline__ unsigned pack2bf(float a, float b) {
    union { float f; unsigned u; } ca, cb; ca.f = a; cb.f = b;
    return __builtin_amdgcn_perm(cb.u + 0x8000u, ca.u + 0x8000u, 0x07060302u);
}

#define GLOAD_LDS(g, l) __builtin_amdgcn_global_load_lds( \
    (const __attribute__((address_space(1))) void*)(g),   \
    (__attribute__((address_space(3))) void*)(l), 16, 0, 0)

// ---------------------------------------------------------------------------
// fp32 -> bf16 convert for the three input tensors.
// ---------------------------------------------------------------------------
__global__ __launch_bounds__(256) void cvt3(
    const float* __restrict__ s0, unsigned short* __restrict__ d0, int n0,
    const float* __restrict__ s1, unsigned short* __restrict__ d1, int n1,
    const float* __restrict__ s2, unsigned short* __restrict__ d2, int n2)
{
    long i = ((long)blockIdx.x * 256 + threadIdx.x) * 8;
    const float* s; unsigned short* d; long off;
    if (i < n0)                  { s = s0; d = d0; off = i; }
    else if (i < (long)n0 + n1)  { s = s1; d = d1; off = i - n0; }
    else                         { s = s2; d = d2; off = i - n0 - n1; }
    f32x4 a = *(const f32x4*)(s + off);
    f32x4 b = *(const f32x4*)(s + off + 4);
    u32x4 r;
    r[0] = pack2bf(a[0], a[1]); r[1] = pack2bf(a[2], a[3]);
    r[2] = pack2bf(b[0], b[1]); r[3] = pack2bf(b[2], b[3]);
    *(u32x4*)(d + off) = r;
}

// ---------------------------------------------------------------------------
// GEMM: C[M,N] = A[M,K]*B[N,K]^T, bf16 in, fp32 accum. 128x128 tile, BK=64,
// global_load_lds dwordx4. LDS [128][64] elems, XOR swizzle: logical 16B
// chunk q of row r at physical chunk q ^ (r&7) -> 2-way on banks (free).
// EPI=0: cols<1024 (Q) -> Cq bf16 scaled by 0.125*log2(e) (softmax prefold);
//        cols 1024..2047 (K) -> Cq bf16 unscaled; cols>=2048 (V) packed-
//        scatter to Cv = Vt[(b*16+h)*64+d][l] bf16.
// EPI=1: Cf fp32 + bias.
// ---------------------------------------------------------------------------
template<int EPI>
__global__ __launch_bounds__(256) void gemm16(
    const unsigned short* __restrict__ A, const unsigned short* __restrict__ Bm,
    unsigned short* __restrict__ Cq, unsigned short* __restrict__ Cv,
    float* __restrict__ Cf, const float* __restrict__ bias,
    int N, int K)
{
    __shared__ unsigned short As[128 * 64];
    __shared__ unsigned short Bs[128 * 64];
    const int tid = threadIdx.x, lane = tid & 63, wave = tid >> 6;
    const int quad = lane >> 4, l16 = lane & 15;
    const int wm = (wave >> 1) * 64, wn = (wave & 1) * 64;
    const int m0 = blockIdx.y * 128, n0 = blockIdx.x * 128;

    const int prow = tid >> 3;
    const int qch  = (tid & 7) ^ (prow & 7);
    const unsigned short* gA[4];
    const unsigned short* gB[4];
    #pragma unroll
    for (int c = 0; c < 4; ++c) {
        gA[c] = A + (size_t)(m0 + c * 32 + prow) * K + qch * 8;
        gB[c] = Bm + (size_t)(n0 + c * 32 + prow) * K + qch * 8;
    }
    const int sw = l16 & 7;   // frag-read swizzle

    f32x4 acc[4][4] = {};
    for (int k0 = 0; k0 < K; k0 += 64) {
        __syncthreads();
        #pragma unroll
        for (int c = 0; c < 4; ++c) {
            GLOAD_LDS(gA[c], As + (c * 256 + tid) * 8);
            GLOAD_LDS(gB[c], Bs + (c * 256 + tid) * 8);
            gA[c] += 64; gB[c] += 64;
        }
        __syncthreads();
        #pragma unroll
        for (int s = 0; s < 2; ++s) {
            s16x8 af[4], bf[4];
            const int pc = ((s * 4 + quad) ^ sw) * 8;
            #pragma unroll
            for (int i = 0; i < 4; ++i)
                af[i] = *(const s16x8*)(As + (wm + i * 16 + l16) * 64 + pc);
            #pragma unroll
            for (int j = 0; j < 4; ++j)
                bf[j] = *(const s16x8*)(Bs + (wn + j * 16 + l16) * 64 + pc);
            #pragma unroll
            for (int i = 0; i < 4; ++i)
                #pragma unroll
                for (int j = 0; j < 4; ++j)
                    acc[i][j] = __builtin_amdgcn_mfma_f32_16x16x32_bf16(af[i], bf[j], acc[i][j], 0, 0, 0);
        }
    }

    // epilogue: C/D layout col=lane&15, row=quad*4+reg
    if (EPI == 1) {
        #pragma unroll
        for (int j = 0; j < 4; ++j) {
            int col = n0 + wn + j * 16 + l16;
            float bv = bias[col];
            #pragma unroll
            for (int i = 0; i < 4; ++i)
                #pragma unroll
                for (int r = 0; r < 4; ++r)
                    Cf[(size_t)(m0 + wm + i * 16 + quad * 4 + r) * N + col] = acc[i][j][r] + bv;
        }
    } else if (n0 < 2048) {
        // Q region: prefold softmax scale (1/8) and log2(e) for native exp2
        const float qs = (n0 < 1024) ? 0.18033688f : 1.0f;   // 0.125*log2(e)
        #pragma unroll
        for (int j = 0; j < 4; ++j) {
            int col = n0 + wn + j * 16 + l16;
            #pragma unroll
            for (int i = 0; i < 4; ++i)
                #pragma unroll
                for (int r = 0; r < 4; ++r)
                    Cq[(size_t)(m0 + wm + i * 16 + quad * 4 + r) * 2048 + col] = f2bf(acc[i][j][r] * qs);
        }
    } else {
        // V region: lane's r=0..3 are 4 consecutive l -> one 8B packed store
        #pragma unroll
        for (int j = 0; j < 4; ++j) {
            int dcol = n0 + wn + j * 16 + l16 - 2048;
            int hh = dcol >> 6, dd = dcol & 63;
            #pragma unroll
            for (int i = 0; i < 4; ++i) {
                int row = m0 + wm + i * 16 + quad * 4;
                int bb = row >> 10, l = row & 1023;
                u32x2 pw;
                pw[0] = pack2bf(acc[i][j][0], acc[i][j][1]);
                pw[1] = pack2bf(acc[i][j][2], acc[i][j][3]);
                *(u32x2*)(Cv + (size_t)((bb * 16 + hh) * 64 + dd) * 1024 + l) = pw;
            }
        }
    }
}

// ---------------------------------------------------------------------------
// Flash attention, no-max softmax (Q pre-scaled by 0.125*log2e -> bare exp2),
// S^T trick with kv-permuted K staging so P's packed C-layout registers are
// directly the PV A-fragments (no P LDS round-trip).
// K staging permutation: LDS row rho = 16t+4u+r holds kv = 32(t>>1)+8u+4(t&1)+r.
// R16: 4 waves, 32 q-cols/wave (qb=0,1) sharing each kf/vf LDS read; QBLK=128,
// grid (8,128)=1024 blocks = 4 blocks/CU (one full round). XCD swizzle puts
// each bh's 8 q-tile blocks on one XCD (L2 fill 142->~55MB). K/V LDS double-
// buffered (32.8KB) with 1-sync prefetch: stage(t+1) issued before compute(t),
// drained at top-of-iter t+1 __syncthreads -> staging latency hidden under
// compute. MFMA clusters setprio(1)-wrapped.
// ---------------------------------------------------------------------------
__global__ __launch_bounds__(256) void attn(
    const unsigned short* __restrict__ qk, const unsigned short* __restrict__ Vt,
    unsigned short* __restrict__ O)
{
    __shared__ unsigned short Ks[2 * 64 * 64];   // [buf][rho][d] kv-permuted, swizzled
    __shared__ unsigned short Vs[2 * 64 * 64];   // [buf][d][kv]  natural, swizzled

    // XCD swizzle: lin%8 = XCD (round-robin dispatch). swz chunks the 1024
    // work items so XCD x gets swz in [x*128,(x+1)*128) = bh in [x*16,x*16+16)
    // with all 8 q-tiles of each bh on the same XCD.
    const int lin = blockIdx.y * 8 + blockIdx.x;
    const int swz = (lin & 7) * 128 + (lin >> 3);
    const int qt = swz & 7, bh = swz >> 3;
    const int b = bh >> 4, hh = bh & 15;
    const int q0 = qt * 128;
    const int tid = threadIdx.x, lane = tid & 63, wave = tid >> 6;
    const int quad = lane >> 4, l16 = lane & 15;

    // Q frags direct from global: B-operand, n=q=wave*32+qb*16+l16,
    // k=s*32+quad*8
    s16x8 qf[2][2];
    #pragma unroll
    for (int qb = 0; qb < 2; ++qb) {
        const unsigned short* qrow =
            qk + (size_t)(b * 1024 + q0 + wave * 32 + qb * 16 + l16) * 2048 + hh * 64;
        qf[qb][0] = *(const s16x8*)(qrow + quad * 8);
        qf[qb][1] = *(const s16x8*)(qrow + 32 + quad * 8);
    }

    // Staging: wave covers LDS rows rho0 = wave*16+rl and rho1 = rho0+8
    // (rl = lane>>3); chunk swizzle qc = (lane&7) ^ (rho&7), rho&7 == rl.
    // K source rows are the PERMUTED kv for each rho (t = wave for both).
    const int rl = lane >> 3;
    const int qc = (lane & 7) ^ rl;
    const int u0 = rl >> 2, r0 = rl & 3;
    const int kvbase = 32 * (wave >> 1) + 4 * (wave & 1) + r0;
    const int kv0 = kvbase + 8 * u0;          // for LDS row wave*16 + rl
    const int kv1 = kvbase + 8 * (2 + u0);    // for LDS row wave*16 + 8 + rl
    const unsigned short* srcK0 = qk + (size_t)(b * 1024 + kv0) * 2048 + 1024 + hh * 64 + qc * 8;
    const unsigned short* srcK1 = qk + (size_t)(b * 1024 + kv1) * 2048 + 1024 + hh * 64 + qc * 8;
    const unsigned short* srcV0 = Vt + (size_t)(bh * 64 + wave * 16 + rl) * 1024 + qc * 8;
    const unsigned short* srcV1 = Vt + (size_t)(bh * 64 + wave * 16 + 8 + rl) * 1024 + qc * 8;
    unsigned short* dK0 = Ks + (wave * 16 + rl) * 64 + (lane & 7) * 8;
    unsigned short* dK1 = Ks + (wave * 16 + 8 + rl) * 64 + (lane & 7) * 8;
    unsigned short* dV0 = Vs + (wave * 16 + rl) * 64 + (lane & 7) * 8;
    unsigned short* dV1 = Vs + (wave * 16 + 8 + rl) * 64 + (lane & 7) * 8;

    const int sw = l16 & 7;   // frag-read swizzle

    f32x4 Oacc[4][2] = {};
    float lsum[2] = {0.0f, 0.0f};

    // prologue: stage tile 0 into buffer 0
    GLOAD_LDS(srcK0, dK0);
    GLOAD_LDS(srcK1, dK1);
    GLOAD_LDS(srcV0, dV0);
    GLOAD_LDS(srcV1, dV1);
    srcK0 += (size_t)64 * 2048; srcK1 += (size_t)64 * 2048;
    srcV0 += 64; srcV1 += 64;

    for (int it = 0; it < 16; ++it) {
        // one sync per tile: vmcnt(0) drain proves tile `it` (staged last
        // iter, in flight during its compute) has landed; barrier proves all
        // waves finished reading the buffer about to be overwritten.
        __syncthreads();
        const int cur = (it & 1) << 12;          // 4096-elem buffer offset
        if (it < 15) {
            const int nxt = 4096 - cur;
            GLOAD_LDS(srcK0, dK0 + nxt);
            GLOAD_LDS(srcK1, dK1 + nxt);
            GLOAD_LDS(srcV0, dV0 + nxt);
            GLOAD_LDS(srcV1, dV1 + nxt);
            srcK0 += (size_t)64 * 2048; srcK1 += (size_t)64 * 2048;
            srcV0 += 64; srcV1 += 64;
        }
        const unsigned short* ks = Ks + cur;
        const unsigned short* vs = Vs + cur;

        // S^T = K Q^T : tile t rows = permuted kv, col q; one kf read feeds
        // both q-fragments (kf independent of qb)
        f32x4 Sacc[4][2] = {};
        __builtin_amdgcn_s_setprio(1);
        #pragma unroll
        for (int t = 0; t < 4; ++t) {
            #pragma unroll
            for (int s = 0; s < 2; ++s) {
                s16x8 kf = *(const s16x8*)(ks + (t * 16 + l16) * 64 + ((s * 4 + quad) ^ sw) * 8);
                #pragma unroll
                for (int qb = 0; qb < 2; ++qb)
                    Sacc[t][qb] = __builtin_amdgcn_mfma_f32_16x16x32_bf16(kf, qf[qb][s], Sacc[t][qb], 0, 0, 0);
            }
        }
        __builtin_amdgcn_s_setprio(0);
        // p = 2^s; per-lane row-sum; pack pairs (these ARE the PV A-frags)
        unsigned upw[4][2][2];
        #pragma unroll
        for (int t = 0; t < 4; ++t) {
            #pragma unroll
            for (int qb = 0; qb < 2; ++qb) {
                float p0 = __builtin_amdgcn_exp2f(Sacc[t][qb][0]);
                float p1 = __builtin_amdgcn_exp2f(Sacc[t][qb][1]);
                float p2 = __builtin_amdgcn_exp2f(Sacc[t][qb][2]);
                float p3 = __builtin_amdgcn_exp2f(Sacc[t][qb][3]);
                lsum[qb] += (p0 + p1) + (p2 + p3);
                upw[t][qb][0] = pack2bf(p0, p1);
                upw[t][qb][1] = pack2bf(p2, p3);
            }
        }
        // O += P V^T : A = packed P (register), B = Vs[n=d] (natural);
        // one vf read feeds both q-fragments (vf independent of qb)
        __builtin_amdgcn_s_setprio(1);
        #pragma unroll
        for (int s = 0; s < 2; ++s) {
            s16x8 pf[2];
            #pragma unroll
            for (int qb = 0; qb < 2; ++qb) {
                u32x4 aw;
                aw[0] = upw[2 * s][qb][0];     aw[1] = upw[2 * s][qb][1];
                aw[2] = upw[2 * s + 1][qb][0]; aw[3] = upw[2 * s + 1][qb][1];
                __builtin_memcpy(&pf[qb], &aw, 16);
            }
            #pragma unroll
            for (int jd = 0; jd < 4; ++jd) {
                s16x8 vf = *(const s16x8*)(vs + (jd * 16 + l16) * 64 + ((s * 4 + quad) ^ sw) * 8);
                #pragma unroll
                for (int qb = 0; qb < 2; ++qb)
                    Oacc[jd][qb] = __builtin_amdgcn_mfma_f32_16x16x32_bf16(pf[qb], vf, Oacc[jd][qb], 0, 0, 0);
            }
        }
        __builtin_amdgcn_s_setprio(0);
    }

    // row-sum reduce + write (sum over quads is permutation-invariant)
    #pragma unroll
    for (int qb = 0; qb < 2; ++qb) {
        float ls = lsum[qb];
        ls += __shfl_xor(ls, 16, 64);
        ls += __shfl_xor(ls, 32, 64);
        float rinv[4];
        #pragma unroll
        for (int r = 0; r < 4; ++r)
            rinv[r] = 1.0f / __shfl(ls, quad * 4 + r, 64);
        #pragma unroll
        for (int j = 0; j < 4; ++j)
            #pragma unroll
            for (int r = 0; r < 4; ++r) {
                int row = q0 + wave * 32 + qb * 16 + quad * 4 + r;
                int col = hh * 64 + j * 16 + l16;
                O[(size_t)(b * 1024 + row) * 1024 + col] = f2bf(Oacc[j][qb][r] * rinv[r]);
            }
    }
}

extern "C" void kernel_launch(void* const* d_in, const int* in_sizes, int n_in,
                              void* d_out, int out_size, void* d_ws, size_t ws_size,
                              hipStream_t stream) {
    const float* x     = (const float*)d_in[0];   // [8192,1024]
    const float* w_qkv = (const float*)d_in[1];   // [3072,1024]
    const float* w_out = (const float*)d_in[2];   // [1024,1024]
    const float* b_out = (const float*)d_in[3];   // [1024]
    float* out = (float*)d_out;                   // [8192,1024] fp32

    const int nx = 8192 * 1024, nwq = 3072 * 1024, nwo = 1024 * 1024;
    unsigned short* xb  = (unsigned short*)d_ws;          // 16.8 MB (dead after gemm1)
    unsigned short* wqb = xb + nx;                        //  6.3 MB
    unsigned short* wob = wqb + nwq;                      //  2.1 MB
    unsigned short* qkb = wob + nwo;                      // [8192,2048] Q|K, 33.6 MB
    unsigned short* Vt  = qkb + (size_t)8192 * 2048;      // [128*64,1024], 16.8 MB
    unsigned short* Ob  = xb;                             // alias: xb dead after gemm1

    dim3 blk(256);
    cvt3<<<6144, blk, 0, stream>>>(x, xb, nx, w_qkv, wqb, nwq, w_out, wob, nwo);
    gemm16<0><<<dim3(24, 64), blk, 0, stream>>>(xb, wqb, qkb, Vt, nullptr, nullptr, 3072, 1024);
    attn<<<dim3(8, 128), blk, 0, stream>>>(qkb, Vt, Ob);
    gemm16<1><<<dim3(8, 64), blk, 0, stream>>>(Ob, wob, nullptr, nullptr, out, b_out, 1024, 1024);
}

// Round 7
// 226.896 us; speedup vs baseline: 1.0762x; 1.0511x over previous
//
#include <hip/hip_runtime.h>

// B=8, L=1024, H=1024, NH=16, HD=64. fp32 I/O, bf16 MFMA internals.
// Pipeline: cvt3     : x,w_qkv,w_out fp32 -> bf16                  (~13 us)
//           gemm16<0>: qk = x@w_qkv^T cols<2048; V scatters to Vt  (51.5 GF)
//           attn     : no-max softmax flash attn, S^T trick        (34.4 GF)
//           gemm16<1>: out = O@w_out^T + b_out (fp32 out)          (17.2 GF)
// R17 (attn): back to the R0 attn geometry -- 4 waves, 16 q-cols/wave,
// QBLK=64, grid 2048 blocks = 8 blocks/CU (TLP is the proven latency-hiding
// mechanism: every 4-blocks/CU variant lost) -- plus exactly ONE fix:
// XCD de-interleave. R0's dim3(16,128) grid gives XCD = lin&7 = qt&7, i.e.
// the 16 q-tiles sharing one bh's 256KB K/V scatter across all 8 XCDs
// (measured: FETCH 142MB vs ~50MB ideal, 3x L2 over-fill). Swizzle
// swz=(lin&7)*256+(lin>>3), qt=swz&15, bh=swz>>4 puts each bh on one XCD;
// per-XCD set = 16 bh x 256KB = 4MB ~ L2. setprio kept on MFMA clusters.
// Lessons kept: qb-widening (R14/R16) halves LDS traffic but costs half the
// TLP -> net loss; dbuf at 32.8KB caps occupancy at 4/CU -> net loss.
// gemm16 = proven R0 form (67us/769TF; R11/R12/R13 variants all regressed).

typedef short s16x8 __attribute__((ext_vector_type(8)));
typedef float f32x4 __attribute__((ext_vector_type(4)));
typedef unsigned int u32x2 __attribute__((ext_vector_type(2)));
typedef unsigned int u32x4 __attribute__((ext_vector_type(4)));

__device__ __forceinline__ unsigned short f2bf(float f) {   // RNE
    union { float f; unsigned u; } c; c.f = f;
    return (unsigned short)((c.u + 0x7FFFu + ((c.u >> 16) & 1u)) >> 16);
}
// pack 2 floats -> 2 bf16 (round-half-up) in 3 VALU ops via v_perm
__device__ __forceinline__ unsigned pack2bf(float a, float b) {
    union { float f; unsigned u; } ca, cb; ca.f = a; cb.f = b;
    return __builtin_amdgcn_perm(cb.u + 0x8000u, ca.u + 0x8000u, 0x07060302u);
}

#define GLOAD_LDS(g, l) __builtin_amdgcn_global_load_lds( \
    (const __attribute__((address_space(1))) void*)(g),   \
    (__attribute__((address_space(3))) void*)(l), 16, 0, 0)

// ---------------------------------------------------------------------------
// fp32 -> bf16 convert for the three input tensors.
// ---------------------------------------------------------------------------
__global__ __launch_bounds__(256) void cvt3(
    const float* __restrict__ s0, unsigned short* __restrict__ d0, int n0,
    const float* __restrict__ s1, unsigned short* __restrict__ d1, int n1,
    const float* __restrict__ s2, unsigned short* __restrict__ d2, int n2)
{
    long i = ((long)blockIdx.x * 256 + threadIdx.x) * 8;
    const float* s; unsigned short* d; long off;
    if (i < n0)                  { s = s0; d = d0; off = i; }
    else if (i < (long)n0 + n1)  { s = s1; d = d1; off = i - n0; }
    else                         { s = s2; d = d2; off = i - n0 - n1; }
    f32x4 a = *(const f32x4*)(s + off);
    f32x4 b = *(const f32x4*)(s + off + 4);
    u32x4 r;
    r[0] = pack2bf(a[0], a[1]); r[1] = pack2bf(a[2], a[3]);
    r[2] = pack2bf(b[0], b[1]); r[3] = pack2bf(b[2], b[3]);
    *(u32x4*)(d + off) = r;
}

// ---------------------------------------------------------------------------
// GEMM: C[M,N] = A[M,K]*B[N,K]^T, bf16 in, fp32 accum. 128x128 tile, BK=64,
// global_load_lds dwordx4. LDS [128][64] elems, XOR swizzle: logical 16B
// chunk q of row r at physical chunk q ^ (r&7) -> 2-way on banks (free).
// EPI=0: cols<1024 (Q) -> Cq bf16 scaled by 0.125*log2(e) (softmax prefold);
//        cols 1024..2047 (K) -> Cq bf16 unscaled; cols>=2048 (V) packed-
//        scatter to Cv = Vt[(b*16+h)*64+d][l] bf16.
// EPI=1: Cf fp32 + bias.
// ---------------------------------------------------------------------------
template<int EPI>
__global__ __launch_bounds__(256) void gemm16(
    const unsigned short* __restrict__ A, const unsigned short* __restrict__ Bm,
    unsigned short* __restrict__ Cq, unsigned short* __restrict__ Cv,
    float* __restrict__ Cf, const float* __restrict__ bias,
    int N, int K)
{
    __shared__ unsigned short As[128 * 64];
    __shared__ unsigned short Bs[128 * 64];
    const int tid = threadIdx.x, lane = tid & 63, wave = tid >> 6;
    const int quad = lane >> 4, l16 = lane & 15;
    const int wm = (wave >> 1) * 64, wn = (wave & 1) * 64;
    const int m0 = blockIdx.y * 128, n0 = blockIdx.x * 128;

    const int prow = tid >> 3;
    const int qch  = (tid & 7) ^ (prow & 7);
    const unsigned short* gA[4];
    const unsigned short* gB[4];
    #pragma unroll
    for (int c = 0; c < 4; ++c) {
        gA[c] = A + (size_t)(m0 + c * 32 + prow) * K + qch * 8;
        gB[c] = Bm + (size_t)(n0 + c * 32 + prow) * K + qch * 8;
    }
    const int sw = l16 & 7;   // frag-read swizzle

    f32x4 acc[4][4] = {};
    for (int k0 = 0; k0 < K; k0 += 64) {
        __syncthreads();
        #pragma unroll
        for (int c = 0; c < 4; ++c) {
            GLOAD_LDS(gA[c], As + (c * 256 + tid) * 8);
            GLOAD_LDS(gB[c], Bs + (c * 256 + tid) * 8);
            gA[c] += 64; gB[c] += 64;
        }
        __syncthreads();
        #pragma unroll
        for (int s = 0; s < 2; ++s) {
            s16x8 af[4], bf[4];
            const int pc = ((s * 4 + quad) ^ sw) * 8;
            #pragma unroll
            for (int i = 0; i < 4; ++i)
                af[i] = *(const s16x8*)(As + (wm + i * 16 + l16) * 64 + pc);
            #pragma unroll
            for (int j = 0; j < 4; ++j)
                bf[j] = *(const s16x8*)(Bs + (wn + j * 16 + l16) * 64 + pc);
            #pragma unroll
            for (int i = 0; i < 4; ++i)
                #pragma unroll
                for (int j = 0; j < 4; ++j)
                    acc[i][j] = __builtin_amdgcn_mfma_f32_16x16x32_bf16(af[i], bf[j], acc[i][j], 0, 0, 0);
        }
    }

    // epilogue: C/D layout col=lane&15, row=quad*4+reg
    if (EPI == 1) {
        #pragma unroll
        for (int j = 0; j < 4; ++j) {
            int col = n0 + wn + j * 16 + l16;
            float bv = bias[col];
            #pragma unroll
            for (int i = 0; i < 4; ++i)
                #pragma unroll
                for (int r = 0; r < 4; ++r)
                    Cf[(size_t)(m0 + wm + i * 16 + quad * 4 + r) * N + col] = acc[i][j][r] + bv;
        }
    } else if (n0 < 2048) {
        // Q region: prefold softmax scale (1/8) and log2(e) for native exp2
        const float qs = (n0 < 1024) ? 0.18033688f : 1.0f;   // 0.125*log2(e)
        #pragma unroll
        for (int j = 0; j < 4; ++j) {
            int col = n0 + wn + j * 16 + l16;
            #pragma unroll
            for (int i = 0; i < 4; ++i)
                #pragma unroll
                for (int r = 0; r < 4; ++r)
                    Cq[(size_t)(m0 + wm + i * 16 + quad * 4 + r) * 2048 + col] = f2bf(acc[i][j][r] * qs);
        }
    } else {
        // V region: lane's r=0..3 are 4 consecutive l -> one 8B packed store
        #pragma unroll
        for (int j = 0; j < 4; ++j) {
            int dcol = n0 + wn + j * 16 + l16 - 2048;
            int hh = dcol >> 6, dd = dcol & 63;
            #pragma unroll
            for (int i = 0; i < 4; ++i) {
                int row = m0 + wm + i * 16 + quad * 4;
                int bb = row >> 10, l = row & 1023;
                u32x2 pw;
                pw[0] = pack2bf(acc[i][j][0], acc[i][j][1]);
                pw[1] = pack2bf(acc[i][j][2], acc[i][j][3]);
                *(u32x2*)(Cv + (size_t)((bb * 16 + hh) * 64 + dd) * 1024 + l) = pw;
            }
        }
    }
}

// ---------------------------------------------------------------------------
// Flash attention, no-max softmax (Q pre-scaled by 0.125*log2e -> bare exp2),
// S^T trick with kv-permuted K staging so P's packed C-layout registers are
// directly the PV A-fragments (no P LDS round-trip).
// K staging permutation: LDS row rho = 16t+4u+r holds kv = 32(t>>1)+8u+4(t&1)+r.
// 64 q-rows/block, 2048 blocks = 8 blocks/CU = 32 waves/CU. LDS 16.4 KB.
// R17: XCD de-interleave -- swz=(lin&7)*256+(lin>>3), qt=swz&15, bh=swz>>4
// puts all 16 q-tiles of a bh on one XCD (K/V L2-fill 142MB -> ~55MB).
// MFMA clusters setprio(1)-wrapped.
// ---------------------------------------------------------------------------
__global__ __launch_bounds__(256) void attn(
    const unsigned short* __restrict__ qk, const unsigned short* __restrict__ Vt,
    unsigned short* __restrict__ O)
{
    __shared__ unsigned short Ks[64 * 64];   // [rho][d] kv-permuted, swizzled
    __shared__ unsigned short Vs[64 * 64];   // [d][kv]  natural, swizzled

    // XCD de-interleave: HW round-robins lin%8 across XCDs; swz chunks the
    // 2048 work items so XCD x gets swz in [256x, 256x+256) = bh in
    // [16x, 16x+16), all 16 q-tiles of each bh on the same XCD.
    const int lin = blockIdx.y * 16 + blockIdx.x;
    const int swz = (lin & 7) * 256 + (lin >> 3);
    const int qt = swz & 15, bh = swz >> 4;
    const int b = bh >> 4, hh = bh & 15;
    const int q0 = qt * 64;
    const int tid = threadIdx.x, lane = tid & 63, wave = tid >> 6;
    const int quad = lane >> 4, l16 = lane & 15;

    // Q frags direct from global: B-operand, n=q=wave*16+l16, k=s*32+quad*8
    const unsigned short* qrow =
        qk + (size_t)(b * 1024 + q0 + wave * 16 + l16) * 2048 + hh * 64;
    s16x8 qf[2];
    qf[0] = *(const s16x8*)(qrow + quad * 8);
    qf[1] = *(const s16x8*)(qrow + 32 + quad * 8);

    // Staging: wave covers LDS rows rho0 = wave*16+rl and rho1 = rho0+8
    // (rl = lane>>3); chunk swizzle qc = (lane&7) ^ (rho&7), rho&7 == rl.
    // K source rows are the PERMUTED kv for each rho (t = wave for both).
    const int rl = lane >> 3;
    const int qc = (lane & 7) ^ rl;
    const int u0 = rl >> 2, r0 = rl & 3;
    const int kvbase = 32 * (wave >> 1) + 4 * (wave & 1) + r0;
    const int kv0 = kvbase + 8 * u0;          // for LDS row wave*16 + rl
    const int kv1 = kvbase + 8 * (2 + u0);    // for LDS row wave*16 + 8 + rl
    const unsigned short* srcK0 = qk + (size_t)(b * 1024 + kv0) * 2048 + 1024 + hh * 64 + qc * 8;
    const unsigned short* srcK1 = qk + (size_t)(b * 1024 + kv1) * 2048 + 1024 + hh * 64 + qc * 8;
    const unsigned short* srcV0 = Vt + (size_t)(bh * 64 + wave * 16 + rl) * 1024 + qc * 8;
    const unsigned short* srcV1 = Vt + (size_t)(bh * 64 + wave * 16 + 8 + rl) * 1024 + qc * 8;
    unsigned short* dK0 = Ks + (wave * 16 + rl) * 64 + (lane & 7) * 8;
    unsigned short* dK1 = Ks + (wave * 16 + 8 + rl) * 64 + (lane & 7) * 8;
    unsigned short* dV0 = Vs + (wave * 16 + rl) * 64 + (lane & 7) * 8;
    unsigned short* dV1 = Vs + (wave * 16 + 8 + rl) * 64 + (lane & 7) * 8;

    const int sw = l16 & 7;   // frag-read swizzle

    f32x4 Oacc[4] = {};
    float lsum = 0.0f;

    for (int kv = 0; kv < 1024; kv += 64) {
        __syncthreads();
        GLOAD_LDS(srcK0, dK0);
        GLOAD_LDS(srcK1, dK1);
        GLOAD_LDS(srcV0, dV0);
        GLOAD_LDS(srcV1, dV1);
        srcK0 += (size_t)64 * 2048; srcK1 += (size_t)64 * 2048;
        srcV0 += 64; srcV1 += 64;
        __syncthreads();   // vmcnt(0) drain -> K,V in LDS

        // S^T = K Q^T : tile t rows = permuted kv, col q = l16
        f32x4 Sacc[4] = {};
        __builtin_amdgcn_s_setprio(1);
        #pragma unroll
        for (int t = 0; t < 4; ++t) {
            #pragma unroll
            for (int s = 0; s < 2; ++s) {
                s16x8 kf = *(const s16x8*)(Ks + (t * 16 + l16) * 64 + ((s * 4 + quad) ^ sw) * 8);
                Sacc[t] = __builtin_amdgcn_mfma_f32_16x16x32_bf16(kf, qf[s], Sacc[t], 0, 0, 0);
            }
        }
        __builtin_amdgcn_s_setprio(0);
        // p = 2^s; per-lane row-sum; pack pairs (these ARE the PV A-frags)
        unsigned upw[4][2];
        #pragma unroll
        for (int t = 0; t < 4; ++t) {
            float p0 = __builtin_amdgcn_exp2f(Sacc[t][0]);
            float p1 = __builtin_amdgcn_exp2f(Sacc[t][1]);
            float p2 = __builtin_amdgcn_exp2f(Sacc[t][2]);
            float p3 = __builtin_amdgcn_exp2f(Sacc[t][3]);
            lsum += (p0 + p1) + (p2 + p3);
            upw[t][0] = pack2bf(p0, p1);
            upw[t][1] = pack2bf(p2, p3);
        }
        // O += P V^T : A = packed P (register), B = Vs[n=d] (natural)
        __builtin_amdgcn_s_setprio(1);
        #pragma unroll
        for (int s = 0; s < 2; ++s) {
            u32x4 aw;
            aw[0] = upw[2 * s][0];     aw[1] = upw[2 * s][1];
            aw[2] = upw[2 * s + 1][0]; aw[3] = upw[2 * s + 1][1];
            s16x8 pf;
            __builtin_memcpy(&pf, &aw, 16);
            #pragma unroll
            for (int jd = 0; jd < 4; ++jd) {
                s16x8 vf = *(const s16x8*)(Vs + (jd * 16 + l16) * 64 + ((s * 4 + quad) ^ sw) * 8);
                Oacc[jd] = __builtin_amdgcn_mfma_f32_16x16x32_bf16(pf, vf, Oacc[jd], 0, 0, 0);
            }
        }
        __builtin_amdgcn_s_setprio(0);
    }

    // row-sum reduce + write (sum over quads is permutation-invariant)
    lsum += __shfl_xor(lsum, 16, 64);
    lsum += __shfl_xor(lsum, 32, 64);
    float rinv[4];
    #pragma unroll
    for (int r = 0; r < 4; ++r)
        rinv[r] = 1.0f / __shfl(lsum, quad * 4 + r, 64);
    #pragma unroll
    for (int j = 0; j < 4; ++j)
        #pragma unroll
        for (int r = 0; r < 4; ++r) {
            int row = q0 + wave * 16 + quad * 4 + r;
            int col = hh * 64 + j * 16 + l16;
            O[(size_t)(b * 1024 + row) * 1024 + col] = f2bf(Oacc[j][r] * rinv[r]);
        }
}

extern "C" void kernel_launch(void* const* d_in, const int* in_sizes, int n_in,
                              void* d_out, int out_size, void* d_ws, size_t ws_size,
                              hipStream_t stream) {
    const float* x     = (const float*)d_in[0];   // [8192,1024]
    const float* w_qkv = (const float*)d_in[1];   // [3072,1024]
    const float* w_out = (const float*)d_in[2];   // [1024,1024]
    const float* b_out = (const float*)d_in[3];   // [1024]
    float* out = (float*)d_out;                   // [8192,1024] fp32

    const int nx = 8192 * 1024, nwq = 3072 * 1024, nwo = 1024 * 1024;
    unsigned short* xb  = (unsigned short*)d_ws;          // 16.8 MB (dead after gemm1)
    unsigned short* wqb = xb + nx;                        //  6.3 MB
    unsigned short* wob = wqb + nwq;                      //  2.1 MB
    unsigned short* qkb = wob + nwo;                      // [8192,2048] Q|K, 33.6 MB
    unsigned short* Vt  = qkb + (size_t)8192 * 2048;      // [128*64,1024], 16.8 MB
    unsigned short* Ob  = xb;                             // alias: xb dead after gemm1

    dim3 blk(256);
    cvt3<<<6144, blk, 0, stream>>>(x, xb, nx, w_qkv, wqb, nwq, w_out, wob, nwo);
    gemm16<0><<<dim3(24, 64), blk, 0, stream>>>(xb, wqb, qkb, Vt, nullptr, nullptr, 3072, 1024);
    attn<<<dim3(16, 128), blk, 0, stream>>>(qkb, Vt, Ob);
    gemm16<1><<<dim3(8, 64), blk, 0, stream>>>(Ob, wob, nullptr, nullptr, out, b_out, 1024, 1024);
}